// Round 8
// baseline (163.206 us; speedup 1.0000x reference)
//
#include <hip/hip_runtime.h>

// filtfilt butter(4,0.2), 512 rows x T=32768 fp32.  R12 == R11 resubmit (infra
// failure last round: "container failed twice", kernel never executed; source
// re-audited: LDS/ws bounds, clamps, Toeplitz/fragment index chain all check).
//  - R10 post-mortem (absmax 0.2656): filtfilt != c*xe at the signal END. The
//    reference's backward pass zero-ICs at the end of the padded signal == it
//    truncates y1 = h*xe at N = T+30 (xe coords); the autocorr FIR implicitly
//    includes the infinite conv tail y1[n>=N] != 0. Extra term
//    err[s] = sum_{k>=N-n} h[k]*y1tail[n+k], nonzero only for the last ~48
//    outputs/row; magnitude Sum|h[16..]| ~ 0.05 x tail ~ 3 = 0.15-0.3 ==
//    observed. Start side exact (zero-pad == zero ICs).
//  - R11 fix: prep exports h[0..64) fp32; last wave: lane 0 reruns the IIR over
//    the tile's last 112 samples (63-step warm, decay 5.6e-7) emitting
//    ytail = y1[N..N+48] to LDS scratch; lanes 48-63 subtract
//    corr[r] = sum_{k>=2063-u} h[k]*ytail[u+k-2063] at the q=7 store.
//  - rest is R10 verbatim: filtfilt == conv with c = autocorr(h), taps per
//    column i cover [i-63, i+32] via 3x mfma_f32_16x16x32_f16 with constant
//    Toeplitz B (B_t[k][j] = c[32t+k-j-32]); fp16 tile [S-17..S+2127) in xe
//    coords staged coalesced; k-permutation-invariant fragment fill; C/D map
//    col=l&15,row=4*(l>>4)+r (HW-verified). Stores 16-lane-contiguous dwords.
//  - grid 2048 blocks x 256 thr = 8192 waves; launch_bounds(256,4).

typedef _Float16 h8 __attribute__((ext_vector_type(8)));
typedef float f32x4 __attribute__((ext_vector_type(4)));

constexpr int kT     = 32768;
constexpr int kOutW  = 2048;            // outputs per wave
constexpr int kWRow  = kT / kOutW;      // 16 waves per row
constexpr int kTPB   = 256;
constexpr int kTileB = 4544;            // 4288 tile + 196 ytail scratch + pad

#define B0c 0.0048243445989025905f
#define B1c 0.019297378395610362f
#define B2c 0.028946067593415543f
#define A1c (-2.369513007182038f)
#define A2c 2.3139884144002064f
#define A3c (-1.0546654058785661f)
#define A4c 0.18737949236818502f
// negated a_i for DFII-transposed step
#define NA1 2.369513007182038f
#define NA2 (-2.3139884144002064f)
#define NA3 1.0546654058785661f
#define NA4 (-0.18737949236818502f)

#define STEPF(xv) do { \
    y  = fmaf(B0c, (xv), z1); \
    z1 = fmaf(NA1, y, fmaf(B1c, (xv), z2)); \
    z2 = fmaf(NA2, y, fmaf(B2c, (xv), z3)); \
    z3 = fmaf(NA3, y, fmaf(B1c, (xv), z4)); \
    z4 = fmaf(NA4, y, B0c * (xv)); \
} while (0)

#define PK(a, b) __builtin_bit_cast(int, __builtin_amdgcn_cvt_pkrtz((a), (b)))

// ---- prep: impulse response h, autocorr c, per-lane Toeplitz B-fragments ----
__global__ void prep_kernel(uint4* __restrict__ ws) {
    __shared__ float h[128];
    const int l = threadIdx.x;
    if (l == 0) {
        float m1 = 0.f, m2 = 0.f, m3 = 0.f, m4 = 0.f;
        const float bb[5] = {B0c, B1c, B2c, B1c, B0c};
        for (int k = 0; k < 128; ++k) {
            float v = (k < 5 ? bb[k] : 0.f);
            v = v - A1c * m1 - A2c * m2 - A3c * m3 - A4c * m4;
            h[k] = v; m4 = m3; m3 = m2; m2 = m1; m1 = v;
        }
    }
    __syncthreads();
    #pragma unroll
    for (int t = 0; t < 3; ++t) {
        h8 f;
        #pragma unroll
        for (int e = 0; e < 8; ++e) {
            int m  = 32 * t + 8 * (l >> 4) + e - (l & 15) - 32;
            int am = m < 0 ? -m : m;
            float c0 = 0.f, c1 = 0.f, c2 = 0.f, c3 = 0.f;
            int k = 0;
            for (; k + 3 + am < 128; k += 4) {
                c0 += h[k]     * h[k + am];
                c1 += h[k + 1] * h[k + 1 + am];
                c2 += h[k + 2] * h[k + 2 + am];
                c3 += h[k + 3] * h[k + 3 + am];
            }
            for (; k + am < 128; ++k) c0 += h[k] * h[k + am];
            f[e] = (_Float16)(c0 + c1 + c2 + c3);
        }
        ws[t * 64 + l] = __builtin_bit_cast(uint4, f);
    }
    // export h[0..64) fp32 for the end-correction (bytes [3072, 3328))
    ((float*)(ws + 192))[l] = h[l];
}

// ---- main: stage fp16 tile, 8 x (3 MFMA) per wave, coalesced stores ----
__global__ __launch_bounds__(kTPB, 4)
void filtfilt_kernel(const float* __restrict__ x, float* __restrict__ out,
                     const uint4* __restrict__ ws) {
    __shared__ __align__(16) char lds[4][kTileB];
    const int t   = threadIdx.x;
    const int l   = t & 63;
    const int wv  = t >> 6;
    const int W   = blockIdx.x * 4 + wv;
    const int row = W >> 4;
    const int sw  = W & (kWRow - 1);
    const int S   = sw * kOutW;
    const float* __restrict__ xr = x + (size_t)row * kT;
    float* __restrict__ outr     = out + (size_t)row * kT;
    char* Lb = lds[wv];

    // constant Toeplitz B fragments (issue early; latency hidden by staging)
    uint4 b0q = ws[l], b1q = ws[64 + l], b2q = ws[128 + l];

    // stage: tile sample d <-> xe[S-17+d] <-> x[S-32+d] in the interior
    #pragma unroll
    for (int i = 0; i < 8; ++i) {
        int xi = S - 32 + 256 * i + 4 * l;
        xi = xi < 0 ? 0 : (xi > kT - 4 ? kT - 4 : xi);   // row-edge clamp
        float4 v = *(const float4*)(xr + xi);
        int2 wi = { PK(v.x, v.y), PK(v.z, v.w) };
        *(int2*)(Lb + 512 * i + 8 * l) = wi;
    }
    if (l < 24) {                                        // tail d in [2048,2144)
        int xi = S + 2016 + 4 * l;
        xi = xi > kT - 4 ? kT - 4 : xi;
        float4 v = *(const float4*)(xr + xi);
        int2 wi = { PK(v.x, v.y), PK(v.z, v.w) };
        *(int2*)(Lb + 4096 + 8 * l) = wi;
    }
    // edge fixups: first wave of row: d in [0,32) = zeros + left odd-ext
    if (sw == 0 && l < 32) {
        float v = 0.f;
        if (l >= 17) v = fmaf(2.f, xr[0], -xr[32 - l]);
        *(_Float16*)(Lb + 2 * l) = (_Float16)v;
    }
    // last wave of row: d in [2080,2144) = right odd-ext + zeros
    if (sw == kWRow - 1) {
        float v = 0.f;
        if (l < 15) v = fmaf(2.f, xr[kT - 1], -xr[kT - 2 - l]);
        *(_Float16*)(Lb + 2 * (2080 + l)) = (_Float16)v;
    }
    asm volatile("s_waitcnt lgkmcnt(0)" ::: "memory");

    // ---- end-correction (last wave only): ytail = y1[N..N+48] -> scratch ----
    // tile d=2095 <-> xe[N] (N = T+30 in xe coords); d in [2032,2144) feeds a
    // zero-IC warm (63 steps, pole decay 5.6e-7) then 49 emitted tail samples.
    if (sw == kWRow - 1) {
        if (l == 0) {
            h8 tv[14];
            #pragma unroll
            for (int i = 0; i < 14; ++i) tv[i] = *(const h8*)(Lb + 4064 + 16 * i);
            float z1 = 0.f, z2 = 0.f, z3 = 0.f, z4 = 0.f, y;
            #pragma unroll
            for (int i = 0; i < 14; ++i) {
                #pragma unroll
                for (int e = 0; e < 8; ++e) {
                    STEPF((float)tv[i][e]);
                    int d = 2032 + 8 * i + e;
                    if (d >= 2095) *(float*)(Lb + 4288 + 4 * (d - 2095)) = y;
                }
            }
        }
        asm volatile("s_waitcnt lgkmcnt(0)" ::: "memory");
    }
    float corr[4] = {0.f, 0.f, 0.f, 0.f};
    if (sw == kWRow - 1 && (l >> 4) == 3) {
        const float* hws = (const float*)(ws + 192);
        #pragma unroll
        for (int r = 0; r < 4; ++r) {
            int u    = 1984 + 16 * r + (l & 15);     // output offset (q=7 rows)
            int kmin = 2063 - u;                     // >=64 -> no correction
            float c = 0.f;
            for (int k = kmin; k < 64; ++k)
                c += hws[k] * *(const float*)(Lb + 4288 + 4 * (u + k - 2063));
            corr[r] = c;
        }
    }

    const h8 B0f = __builtin_bit_cast(h8, b0q);
    const h8 B1f = __builtin_bit_cast(h8, b1q);
    const h8 B2f = __builtin_bit_cast(h8, b2q);

    const int lg = l >> 4, lc = l & 15;
    #pragma unroll
    for (int q = 0; q < 8; ++q) {
        // A row i = lc covers outputs [S+256q+16i, +16); lane reads 8 contiguous
        // fp16 at logical k = 8*lg+e  (16B-aligned by construction)
        const char* p = Lb + 512 * q + 32 * lc + 16 * lg;
        h8 a0 = *(const h8*)p;
        h8 a1 = *(const h8*)(p + 64);
        h8 a2 = *(const h8*)(p + 128);
        f32x4 acc = {0.f, 0.f, 0.f, 0.f};
        acc = __builtin_amdgcn_mfma_f32_16x16x32_f16(a0, B0f, acc, 0, 0, 0);
        acc = __builtin_amdgcn_mfma_f32_16x16x32_f16(a1, B1f, acc, 0, 0, 0);
        acc = __builtin_amdgcn_mfma_f32_16x16x32_f16(a2, B2f, acc, 0, 0, 0);
        // D: col=lc, row=4*lg+r  ->  out = S+256q+64*lg+16r+lc (coalesced x16)
        const int o0 = S + 256 * q + 64 * lg + lc;
        if (q == 7) {
            outr[o0]      = acc[0] - corr[0];
            outr[o0 + 16] = acc[1] - corr[1];
            outr[o0 + 32] = acc[2] - corr[2];
            outr[o0 + 48] = acc[3] - corr[3];
        } else {
            outr[o0]      = acc[0];
            outr[o0 + 16] = acc[1];
            outr[o0 + 32] = acc[2];
            outr[o0 + 48] = acc[3];
        }
    }
}

extern "C" void kernel_launch(void* const* d_in, const int* in_sizes, int n_in,
                              void* d_out, int out_size, void* d_ws, size_t ws_size,
                              hipStream_t stream) {
    const float* x = (const float*)d_in[0];
    float* outp    = (float*)d_out;
    const int rows = in_sizes[0] / kT;                 // 512
    prep_kernel<<<1, 64, 0, stream>>>((uint4*)d_ws);
    const int blocks = rows * kWRow * 64 / kTPB;       // 2048
    filtfilt_kernel<<<blocks, kTPB, 0, stream>>>(x, outp, (const uint4*)d_ws);
}